// Round 6
// baseline (594.340 us; speedup 1.0000x reference)
//
#include <hip/hip_runtime.h>
#include <math.h>

#define S      384
#define N0     192
#define NE     191
#define MAXADJ 16
#define E50    1.9287498e-22f   // exp(-50)
#define NB     96               // persistent grid blocks

// float workspace offsets
#define OFF_W     0
#define OFF_WT    36864
#define OFF_PHIE  73728
#define OFF_MSGF  147456
#define OFF_MSGB  221184
#define OFF_MXF   294912
#define OFF_MXB   368640
#define OFF_SBT   442368
#define OFF_BASET 516096
#define OFF_U     589824
#define OFF_V     590016
#define OFF_MAXF  590400
#define OFF_MAXB  590592
#define OFF_HIF   590784
#define OFF_LOF   590976
#define OFF_HIB   591168
#define OFF_LOB   591360
#define OFF_UHI   591552
#define OFF_BAR   591616     // cnt at [0], gen at [32] (separate 128B lines)
#define OFF_INT   591744
// int offsets relative to (int*)(ws + OFF_INT)
#define IOFF_DSTF 0
#define IOFF_DSTB 192
#define IOFF_CNTF 384
#define IOFF_CNTB 576
#define IOFF_ADJF 768
#define IOFF_ADJB (768 + 192*MAXADJ)

// ---------------------------------------------------------------------------
__global__ __launch_bounds__(256) void k_setup(
    const int* __restrict__ E1f, const int* __restrict__ E1b,
    const float* __restrict__ cost, const float* __restrict__ constr,
    float* __restrict__ ws)
{
    int tid = blockIdx.x * 256 + threadIdx.x;
    int nt  = gridDim.x * 256;

    for (int idx = tid; idx < 192 * 192; idx += nt) {
        int k = idx / 192, s = idx % 192;
        float w = __expf(-50.f * (1.f - constr[idx]));
        ws[OFF_W + idx] = w;               // W[k][s]
        ws[OFF_WT + s * 192 + k] = w;      // WT[k][s] = W[s][k]
    }
    for (int idx = tid; idx < 192 * S; idx += nt) {
        int j = idx / S, i = idx % S;
        ws[OFF_PHIE + idx] = (i < N0) ? -10.f * cost[j * N0 + i] : 0.f;
        ws[OFF_MSGF + idx] = 0.f;
        ws[OFF_MSGB + idx] = 0.f;
        ws[OFF_MXF + idx]  = 0.f;
        ws[OFF_MXB + idx]  = (j < NE) ? 1.f : 0.f;
    }
    for (int i = tid; i < S; i += nt) ws[OFF_V + i] = 0.f;
    for (int i = tid; i < 192; i += nt) {
        ws[OFF_U + i] = 0.f;
        ws[OFF_MAXF + i] = 0.f; ws[OFF_MAXB + i] = 0.f;
        ws[OFF_HIF + i] = 0.f;  ws[OFF_LOF + i] = 0.f;
        ws[OFF_HIB + i] = (i < NE) ? 192.f : 0.f;
        ws[OFF_LOB + i] = (i < NE) ? 192.f : 0.f;
    }
    if (tid == 0) {
        ws[OFF_UHI] = 0.f;
        unsigned* bar = (unsigned*)(ws + OFF_BAR);
        bar[0] = 0u;   // cnt
        bar[32] = 0u;  // gen
    }

    int* ip = (int*)(ws + OFF_INT);
    for (int e = tid; e < 192; e += nt) {
        ip[IOFF_DSTF + e] = (e < NE) ? E1f[2 * e + 1] : 0;
        ip[IOFF_DSTB + e] = (e < NE) ? E1b[2 * e + 1] : 0;
    }
    for (int b = tid; b < 192; b += nt) {
        int cf = 0, cb = 0;
        for (int e = 0; e < NE; ++e) {
            if (E1f[2 * e + 1] == b && cf < MAXADJ) ip[IOFF_ADJF + b * MAXADJ + cf++] = e;
            if (E1b[2 * e + 1] == b && cb < MAXADJ) ip[IOFF_ADJB + b * MAXADJ + cb++] = e;
        }
        ip[IOFF_CNTF + b] = cf;
        ip[IOFF_CNTB + b] = cb;
    }
}

// ---------------------------------------------------------------------------
// hand-rolled generation grid barrier (agent scope, self-resetting)
__device__ __forceinline__ void gbar(unsigned* bar)
{
    __syncthreads();
    if (threadIdx.x == 0) {
        unsigned* cnt = bar;
        unsigned* gen = bar + 32;
        unsigned g = __hip_atomic_fetch_add(gen, 0u, __ATOMIC_RELAXED,
                                            __HIP_MEMORY_SCOPE_AGENT);
        unsigned a = __hip_atomic_fetch_add(cnt, 1u, __ATOMIC_RELEASE,
                                            __HIP_MEMORY_SCOPE_AGENT);
        if (a == NB - 1) {
            __hip_atomic_exchange(cnt, 0u, __ATOMIC_RELAXED,
                                  __HIP_MEMORY_SCOPE_AGENT);
            __hip_atomic_fetch_add(gen, 1u, __ATOMIC_RELEASE,
                                   __HIP_MEMORY_SCOPE_AGENT);
        } else {
            while (__hip_atomic_fetch_add(gen, 0u, __ATOMIC_RELAXED,
                                          __HIP_MEMORY_SCOPE_AGENT) == g)
                __builtin_amdgcn_s_sleep(4);
        }
    }
    __threadfence();
    __syncthreads();
}

// ---------------------------------------------------------------------------
// msg tail: given GEMV result acc (thread t owns s=t<192), do the msg update,
// min-reduce, MX write, colsums. Identical math to round-5 k_msg.
__device__ __forceinline__ void msg_tail(
    float* __restrict__ ws, const int* __restrict__ ip,
    int e, int fwd, float acc, int t, float* red, float* red2)
{
    float* MSG = ws + (fwd ? OFF_MSGF : OFF_MSGB);
    float* MX  = ws + (fwd ? OFF_MXF  : OFF_MXB);

    float mPrev = fwd ? ws[OFF_MAXB + e] : ws[OFF_MAXF + e];
    float hi    = fwd ? ws[OFF_HIB + e]  : ws[OFF_HIF + e];
    float lo    = fwd ? ws[OFF_LOB + e]  : ws[OFF_LOF + e];
    float addLo = fwd ? hi : E50 * hi;
    float yHi   = fwd ? (hi + E50 * lo) : (lo + hi);
    float lyHi  = __logf(yHi);

    int d = fwd ? ip[IOFF_DSTF + e] : ip[IOFF_DSTB + e];
    float uD = ws[OFF_U + d];
    const float* V = ws + OFF_V;

    int s1 = t, s2 = t + 256;
    float bt1, bt2 = 0.f;
    if (fwd) {
        bt1 = ws[OFF_BASET + d * S + s1];
        if (s2 < S) bt2 = ws[OFF_BASET + d * S + s2];
    } else {
        int cF = ip[IOFF_CNTF + d];
        const int* aF = ip + IOFF_ADJF + d * MAXADJ;
        bt1 = ws[OFF_PHIE + d * S + s1] + ws[OFF_SBT + d * S + s1];
        if (s2 < S) bt2 = ws[OFF_PHIE + d * S + s2] + ws[OFF_SBT + d * S + s2];
        for (int q = 0; q < cF; ++q) {
            const float* mr = ws + OFF_MSGF + aF[q] * S;
            bt1 += mr[s1];
            if (s2 < S) bt2 += mr[s2];
        }
    }

    float logy1 = (s1 < 192) ? __logf(acc + addLo) : lyHi;
    float x1 = 0.5f * (MSG[e * S + s1] + uD + V[s1] - bt1 + mPrev + logy1);
    float x2 = 1e30f;
    if (s2 < S) {
        x2 = 0.5f * (MSG[e * S + s2] + uD + V[s2] - bt2 + mPrev + lyHi);
        MSG[e * S + s2] = x2;
    }
    MSG[e * S + s1] = x1;

    red[t] = fminf(x1, x2);
    __syncthreads();
    for (int o = 128; o; o >>= 1) {
        if (t < o) red[t] = fminf(red[t], red[t + o]);
        __syncthreads();
    }
    float mn = red[0];
    __syncthreads();

    float mx1 = __expf(mn - x1);
    float mx2 = (s2 < S) ? __expf(mn - x2) : 0.f;
    MX[e * S + s1] = mx1;
    if (s2 < S) MX[e * S + s2] = mx2;
    if (t == 0) {
        if (fwd) ws[OFF_MAXF + e] = -mn; else ws[OFF_MAXB + e] = -mn;
    }

    red[t]  = (t < 192) ? mx1 : 0.f;
    red2[t] = ((t >= 192) ? mx1 : 0.f) + mx2;
    __syncthreads();
    for (int o = 128; o; o >>= 1) {
        if (t < o) { red[t] += red[t + o]; red2[t] += red2[t + o]; }
        __syncthreads();
    }
    if (t == 0) {
        if (fwd) { ws[OFF_LOF + e] = red[0]; ws[OFF_HIF + e] = red2[0]; }
        else     { ws[OFF_LOB + e] = red[0]; ws[OFF_HIB + e] = red2[0]; }
    }
    __syncthreads();
}

// msg phase: 2 edges per block, W tile staged in LDS once for both
__device__ __forceinline__ void msg_phase(
    float* __restrict__ ws, const int* __restrict__ ip,
    int bid, int t, int fwd,
    float* la, float (*mxs)[192], float* red, float* red2)
{
    int e0 = bid * 2, e1 = bid * 2 + 1;
    const float* Wm   = ws + (fwd ? OFF_W   : OFF_WT);
    const float* MXin = ws + (fwd ? OFF_MXB : OFF_MXF);

    if (t < 192) {
        mxs[0][t] = MXin[e0 * S + t];
        mxs[1][t] = (e1 < NE) ? MXin[e1 * S + t] : 0.f;
    }

    float acc0 = 0.f, acc1 = 0.f;
    for (int k0 = 0; k0 < 192; k0 += 32) {
        __syncthreads();
        for (int q = t; q < 32 * 192; q += 256)
            la[q] = Wm[k0 * 192 + q];
        __syncthreads();
        if (t < 192) {
#pragma unroll 8
            for (int kk = 0; kk < 32; ++kk) {
                float wv = la[kk * 192 + t];
                acc0 += wv * mxs[0][k0 + kk];
                acc1 += wv * mxs[1][k0 + kk];
            }
        }
    }
    __syncthreads();
    msg_tail(ws, ip, e0, fwd, acc0, t, red, red2);
    if (e1 < NE)
        msg_tail(ws, ip, e1, fwd, acc1, t, red, red2);
}

// ---------------------------------------------------------------------------
__global__ __launch_bounds__(256) void k_iter(float* __restrict__ ws,
                                              float* __restrict__ out)
{
    const int bid = blockIdx.x, t = threadIdx.x;
    const int l = t & 63, w = t >> 6;
    unsigned* bar = (unsigned*)(ws + OFF_BAR);
    const int* ip = (const int*)(ws + OFF_INT);

    __shared__ float la[32 * 192];
    __shared__ float mxs[2][192];
    __shared__ float red[256], red2[256];
    __shared__ float vm[4][5], vs[4][5];

    for (int step = 0; step < 8; ++step) {
        // ---- PH_A: gather sums, write BASET/SBT, u[j]; uhi ----
        if (w < 2) {
            int j = bid * 2 + w;
            int cF = ip[IOFF_CNTF + j], cB = ip[IOFF_CNTB + j];
            const int* aF = ip + IOFF_ADJF + j * MAXADJ;
            const int* aB = ip + IOFF_ADJB + j * MAXADJ;
            float sft[6] = {0,0,0,0,0,0}, sbt[6] = {0,0,0,0,0,0};
            for (int q = 0; q < cF; ++q) {
                const float* mr = ws + OFF_MSGF + aF[q] * S;
#pragma unroll
                for (int p = 0; p < 6; ++p) sft[p] += mr[l + 64 * p];
            }
            for (int q = 0; q < cB; ++q) {
                const float* mr = ws + OFF_MSGB + aB[q] * S;
#pragma unroll
                for (int p = 0; p < 6; ++p) sbt[p] += mr[l + 64 * p];
            }
            float x[6], m = -1e30f;
#pragma unroll
            for (int p = 0; p < 6; ++p) {
                int i = l + 64 * p;
                float bt = ws[OFF_PHIE + j * S + i] + sft[p] + sbt[p];
                ws[OFF_BASET + j * S + i] = bt;
                ws[OFF_SBT + j * S + i]   = sbt[p];
                x[p] = bt - ws[OFF_V + i];
                m = fmaxf(m, x[p]);
            }
#pragma unroll
            for (int o = 32; o; o >>= 1) m = fmaxf(m, __shfl_xor(m, o, 64));
            float sm = 0.f;
#pragma unroll
            for (int p = 0; p < 6; ++p) sm += __expf(x[p] - m);
#pragma unroll
            for (int o = 32; o; o >>= 1) sm += __shfl_xor(sm, o, 64);
            if (l == 0) ws[OFF_U + j] = m + __logf(sm);
        } else if (bid == 0 && w == 2) {
            float xx[6], m = -1e30f;
#pragma unroll
            for (int q = 0; q < 6; ++q) {
                xx[q] = -ws[OFF_V + l + 64 * q];
                m = fmaxf(m, xx[q]);
            }
#pragma unroll
            for (int o = 32; o; o >>= 1) m = fmaxf(m, __shfl_xor(m, o, 64));
            float sm = 0.f;
#pragma unroll
            for (int q = 0; q < 6; ++q) sm += __expf(xx[q] - m);
#pragma unroll
            for (int o = 32; o; o >>= 1) sm += __shfl_xor(sm, o, 64);
            if (l == 0) ws[OFF_UHI] = m + __logf(sm);
        }
        gbar(bar);

        // ---- PH_B: v[i] for i = 4*bid .. 4*bid+3 ----
        {
            int il = l & 3;
            int i  = bid * 4 + il;
            int jg = (w << 4) + (l >> 2);
            float m = -1e30f, sm = 0.f;
            for (int j = jg; j < 192; j += 64) {
                float x = ws[OFF_BASET + j * S + i] - ws[OFF_U + j];
                float mn = fmaxf(m, x);
                sm = sm * __expf(m - mn) + __expf(x - mn);
                m = mn;
            }
#pragma unroll
            for (int off = 4; off < 64; off <<= 1) {
                float m2 = __shfl_xor(m, off, 64);
                float s2 = __shfl_xor(sm, off, 64);
                float mn = fmaxf(m, m2);
                sm = sm * __expf(m - mn) + s2 * __expf(m2 - mn);
                m = mn;
            }
            if (l < 4) { vm[w][l] = m; vs[w][l] = sm; }
            __syncthreads();
            if (t < 4) {
                float M = vm[0][t], Ss = vs[0][t];
#pragma unroll
                for (int g2 = 1; g2 < 4; ++g2) {
                    float m2 = vm[g2][t], s2 = vs[g2][t];
                    float mn = fmaxf(M, m2);
                    Ss = Ss * __expf(M - mn) + s2 * __expf(m2 - mn);
                    M = mn;
                }
                float xt = __logf(192.f) - ws[OFF_UHI];
                float mn = fmaxf(M, xt);
                Ss = Ss * __expf(M - mn) + __expf(xt - mn);
                ws[OFF_V + bid * 4 + t] = mn + __logf(Ss);
            }
        }
        gbar(bar);

        // ---- PH_C: msg_f ----
        msg_phase(ws, ip, bid, t, 1, la, mxs, red, red2);
        gbar(bar);

        // ---- PH_D: msg_b ----
        msg_phase(ws, ip, bid, t, 0, la, mxs, red, red2);
        gbar(bar);
    }

    // ---- final: 4 rows per block ----
    const float* V = ws + OFF_V;
    float uhi = ws[OFF_UHI];
    for (int r = 0; r < 4; ++r) {
        int a = bid * 4 + r;
        if (a < 192) {
            float ua = ws[OFF_U + a];
            int cF = ip[IOFF_CNTF + a], cB = ip[IOFF_CNTB + a];
            const int* aF = ip + IOFF_ADJF + a * MAXADJ;
            const int* aB = ip + IOFF_ADJB + a * MAXADJ;
            for (int b = t; b < S; b += 256) {
                float bt = ws[OFF_PHIE + a * S + b];
                for (int q = 0; q < cF; ++q) bt += ws[OFF_MSGF + aF[q] * S + b];
                for (int q = 0; q < cB; ++q) bt += ws[OFF_MSGB + aB[q] * S + b];
                out[a * S + b] = __expf(fminf(bt - ua - V[b], 0.f));
            }
        } else {
            for (int b = t; b < S; b += 256)
                out[a * S + b] = __expf(fminf(-uhi - V[b], 0.f));
        }
    }
}

// ---------------------------------------------------------------------------
extern "C" void kernel_launch(void* const* d_in, const int* in_sizes, int n_in,
                              void* d_out, int out_size, void* d_ws, size_t ws_size,
                              hipStream_t stream)
{
    const int*   E1f    = (const int*)d_in[0];
    const int*   E1b    = (const int*)d_in[1];
    const float* cost   = (const float*)d_in[3];
    const float* constr = (const float*)d_in[4];

    float* ws   = (float*)d_ws;
    float* outp = (float*)d_out;

    k_setup<<<64, 256, 0, stream>>>(E1f, E1b, cost, constr, ws);

    void* args[] = { (void*)&ws, (void*)&outp };
    hipLaunchCooperativeKernel((const void*)k_iter, dim3(NB), dim3(256),
                               args, 0, stream);
}

// Round 7
// 325.088 us; speedup vs baseline: 1.8282x; 1.8282x over previous
//
#include <hip/hip_runtime.h>
#include <math.h>

#define S      384
#define N0     192
#define NE     191
#define MAXADJ 16
#define E50    1.9287498e-22f   // exp(-50)

// float workspace offsets
#define OFF_W     0
#define OFF_WT    36864
#define OFF_PHIE  73728
#define OFF_MSGF  147456
#define OFF_MSGB  221184
#define OFF_MXF   294912
#define OFF_MXB   368640
#define OFF_SBT   442368
#define OFF_BASET 516096
#define OFF_U     589824
#define OFF_V     590016
#define OFF_MAXF  590400
#define OFF_MAXB  590592
#define OFF_HIF   590784
#define OFF_LOF   590976
#define OFF_HIB   591168
#define OFF_LOB   591360
#define OFF_UHI   591552
#define OFF_INT   591616
// int offsets relative to (int*)(ws + OFF_INT)
#define IOFF_DSTF 0
#define IOFF_DSTB 192
#define IOFF_CNTF 384
#define IOFF_CNTB 576
#define IOFF_ADJF 768
#define IOFF_ADJB (768 + 192*MAXADJ)

// ---------------------------------------------------------------------------
__global__ __launch_bounds__(256) void k_setup(
    const int* __restrict__ E1f, const int* __restrict__ E1b,
    const float* __restrict__ cost, const float* __restrict__ constr,
    float* __restrict__ ws)
{
    int tid = blockIdx.x * 256 + threadIdx.x;
    int nt  = gridDim.x * 256;

    for (int idx = tid; idx < 192 * 192; idx += nt) {
        int k = idx / 192, s = idx % 192;
        float w = __expf(-50.f * (1.f - constr[idx]));
        ws[OFF_W + idx] = w;               // W[k][s]  (fwd GEMV weights)
        ws[OFF_WT + s * 192 + k] = w;      // WT[k][s] = W[s][k] (bwd)
    }
    for (int idx = tid; idx < 192 * S; idx += nt) {
        int j = idx / S, i = idx % S;
        ws[OFF_PHIE + idx] = (i < N0) ? -10.f * cost[j * N0 + i] : 0.f;
        ws[OFF_MSGF + idx] = 0.f;
        ws[OFF_MSGB + idx] = 0.f;
        ws[OFF_MXF + idx]  = 0.f;
        ws[OFF_MXB + idx]  = (j < NE) ? 1.f : 0.f;   // exp(0-0)=1
    }
    for (int i = tid; i < S; i += nt) ws[OFF_V + i] = 0.f;
    for (int i = tid; i < 192; i += nt) {
        ws[OFF_U + i] = 0.f;
        ws[OFF_MAXF + i] = 0.f; ws[OFF_MAXB + i] = 0.f;
        ws[OFF_HIF + i] = 0.f;  ws[OFF_LOF + i] = 0.f;
        ws[OFF_HIB + i] = (i < NE) ? 192.f : 0.f;
        ws[OFF_LOB + i] = (i < NE) ? 192.f : 0.f;
    }
    if (tid == 0) ws[OFF_UHI] = 0.f;

    int* ip = (int*)(ws + OFF_INT);
    for (int e = tid; e < 192; e += nt) {
        ip[IOFF_DSTF + e] = (e < NE) ? E1f[2 * e + 1] : 0;
        ip[IOFF_DSTB + e] = (e < NE) ? E1b[2 * e + 1] : 0;
    }
    for (int b = tid; b < 192; b += nt) {
        int cf = 0, cb = 0;
        for (int e = 0; e < NE; ++e) {
            if (E1f[2 * e + 1] == b && cf < MAXADJ) ip[IOFF_ADJF + b * MAXADJ + cf++] = e;
            if (E1b[2 * e + 1] == b && cb < MAXADJ) ip[IOFF_ADJB + b * MAXADJ + cb++] = e;
        }
        ip[IOFF_CNTF + b] = cf;
        ip[IOFF_CNTB + b] = cb;
    }
}

// ---------------------------------------------------------------------------
// K1: per row j<192 (one wave each): gather SFT/SBT from msgs, rewrite
//     BASET[j] = phie_neg[j] + sft + sbt, store SBT[j], u[j] = LSE_i(BT-V).
//     Block 48: uhi = LSE_i(-V[i]).
__global__ __launch_bounds__(256) void k_uv1(float* __restrict__ ws)
{
    int bid = blockIdx.x, t = threadIdx.x;
    int l = t & 63, w = t >> 6;
    const float* V = ws + OFF_V;

    if (bid == 48) {
        if (w == 0) {
            float m = -1e30f, x[6];
#pragma unroll
            for (int q = 0; q < 6; ++q) { x[q] = -V[l + 64 * q]; m = fmaxf(m, x[q]); }
#pragma unroll
            for (int o = 32; o; o >>= 1) m = fmaxf(m, __shfl_xor(m, o, 64));
            float sm = 0.f;
#pragma unroll
            for (int q = 0; q < 6; ++q) sm += __expf(x[q] - m);
#pragma unroll
            for (int o = 32; o; o >>= 1) sm += __shfl_xor(sm, o, 64);
            if (l == 0) ws[OFF_UHI] = m + __logf(sm);
        }
        return;
    }

    int j = bid * 4 + w;                    // 48 blocks x 4 waves = 192 rows
    const int* ip = (const int*)(ws + OFF_INT);
    int cF = ip[IOFF_CNTF + j], cB = ip[IOFF_CNTB + j];
    const int* aF = ip + IOFF_ADJF + j * MAXADJ;
    const int* aB = ip + IOFF_ADJB + j * MAXADJ;

    float sft[6] = {0,0,0,0,0,0}, sbt[6] = {0,0,0,0,0,0};
    for (int q = 0; q < cF; ++q) {
        const float* mr = ws + OFF_MSGF + aF[q] * S;
#pragma unroll
        for (int p = 0; p < 6; ++p) sft[p] += mr[l + 64 * p];
    }
    for (int q = 0; q < cB; ++q) {
        const float* mr = ws + OFF_MSGB + aB[q] * S;
#pragma unroll
        for (int p = 0; p < 6; ++p) sbt[p] += mr[l + 64 * p];
    }

    float x[6], m = -1e30f;
#pragma unroll
    for (int p = 0; p < 6; ++p) {
        int i = l + 64 * p;
        float bt = ws[OFF_PHIE + j * S + i] + sft[p] + sbt[p];
        ws[OFF_BASET + j * S + i] = bt;
        ws[OFF_SBT + j * S + i]   = sbt[p];
        x[p] = bt - V[i];
        m = fmaxf(m, x[p]);
    }
#pragma unroll
    for (int o = 32; o; o >>= 1) m = fmaxf(m, __shfl_xor(m, o, 64));
    float sm = 0.f;
#pragma unroll
    for (int p = 0; p < 6; ++p) sm += __expf(x[p] - m);
#pragma unroll
    for (int o = 32; o; o >>= 1) sm += __shfl_xor(sm, o, 64);
    if (l == 0) ws[OFF_U + j] = m + __logf(sm);
}

// ---------------------------------------------------------------------------
// column LSE for v[i]: log( sum_{j<192} exp(BT[j][i]-Ul[j]) + exp(xt) )
__device__ __forceinline__ float col_lse(const float* __restrict__ BT,
                                         const float* __restrict__ Ul,
                                         int i, float xt)
{
    const float* bc = BT + i;
    float m0 = -1e30f, m1 = -1e30f, m2 = -1e30f, m3 = -1e30f;
#pragma unroll 8
    for (int j = 0; j < 192; j += 4) {
        m0 = fmaxf(m0, bc[(j + 0) * S] - Ul[j + 0]);
        m1 = fmaxf(m1, bc[(j + 1) * S] - Ul[j + 1]);
        m2 = fmaxf(m2, bc[(j + 2) * S] - Ul[j + 2]);
        m3 = fmaxf(m3, bc[(j + 3) * S] - Ul[j + 3]);
    }
    float m = fmaxf(fmaxf(fmaxf(m0, m1), fmaxf(m2, m3)), xt);
    float s0 = 0.f, s1 = 0.f, s2 = 0.f, s3 = 0.f;
#pragma unroll 8
    for (int j = 0; j < 192; j += 4) {
        s0 += __expf(bc[(j + 0) * S] - Ul[j + 0] - m);
        s1 += __expf(bc[(j + 1) * S] - Ul[j + 1] - m);
        s2 += __expf(bc[(j + 2) * S] - Ul[j + 2] - m);
        s3 += __expf(bc[(j + 3) * S] - Ul[j + 3] - m);
    }
    return m + __logf((s0 + s1) + (s2 + s3) + __expf(xt - m));
}

// K2/K3: msg update with fused GEMV + colsum. One block per edge.
//  fwd=1: recompute v (pure fn of BASET,u,uhi) for own columns; block 0 publishes V.
//  fwd: y_lo[s] = sum_k W[k][s]*MXB[e][k] ; bt = BASET[d]
//  bwd: y_lo[s] = sum_k WT[k][s]*MXF[e][k]; bt = PHIE[d]+SBT[d]+gather(MSGF,adjF[d])
__global__ __launch_bounds__(256) void k_msg(float* __restrict__ ws, int fwd)
{
    __shared__ float mx[192];
    __shared__ float Ul[192];
    __shared__ float red[256], red2[256];
    int e = blockIdx.x, t = threadIdx.x;
    const int* ip = (const int*)(ws + OFF_INT);

    float* MSG  = ws + (fwd ? OFF_MSGF : OFF_MSGB);
    float* MX   = ws + (fwd ? OFF_MXF  : OFF_MXB);
    const float* MXin = ws + (fwd ? OFF_MXB : OFF_MXF);
    const float* Wm   = ws + (fwd ? OFF_W   : OFF_WT);

    float mPrev = fwd ? ws[OFF_MAXB + e] : ws[OFF_MAXF + e];
    float hi    = fwd ? ws[OFF_HIB + e]  : ws[OFF_HIF + e];
    float lo    = fwd ? ws[OFF_LOB + e]  : ws[OFF_LOF + e];
    float addLo = fwd ? hi : E50 * hi;
    float yHi   = fwd ? (hi + E50 * lo) : (lo + hi);
    float lyHi  = __logf(yHi);

    int d = fwd ? ip[IOFF_DSTF + e] : ip[IOFF_DSTB + e];
    float uD = ws[OFF_U + d];

    if (t < 192) {
        mx[t] = MXin[e * S + t];
        Ul[t] = ws[OFF_U + t];
    }
    __syncthreads();

    int s1 = t, s2 = t + 256;

    // v for this thread's columns
    float v1, v2 = 0.f;
    if (fwd) {
        float xt = __logf(192.f) - ws[OFF_UHI];
        v1 = col_lse(ws + OFF_BASET, Ul, s1, xt);
        if (s2 < S) v2 = col_lse(ws + OFF_BASET, Ul, s2, xt);
        if (e == 0) {                     // publish V for bwd/uv1/final
            ws[OFF_V + s1] = v1;
            if (s2 < S) ws[OFF_V + s2] = v2;
        }
    } else {
        v1 = ws[OFF_V + s1];
        if (s2 < S) v2 = ws[OFF_V + s2];
    }

    // GEMV: y = sum_k Wm[k][s] * mx[k], thread t owns s=t (t<192)
    float acc = 0.f;
    if (t < 192) {
#pragma unroll 8
        for (int k = 0; k < 192; ++k)
            acc += Wm[k * 192 + t] * mx[k];
    }

    // bt for this thread's two columns
    float bt1, bt2 = 0.f;
    if (fwd) {
        bt1 = ws[OFF_BASET + d * S + s1];
        if (s2 < S) bt2 = ws[OFF_BASET + d * S + s2];
    } else {
        int cF = ip[IOFF_CNTF + d];
        const int* aF = ip + IOFF_ADJF + d * MAXADJ;
        bt1 = ws[OFF_PHIE + d * S + s1] + ws[OFF_SBT + d * S + s1];
        if (s2 < S) bt2 = ws[OFF_PHIE + d * S + s2] + ws[OFF_SBT + d * S + s2];
        for (int q = 0; q < cF; ++q) {
            const float* mr = ws + OFF_MSGF + aF[q] * S;
            bt1 += mr[s1];
            if (s2 < S) bt2 += mr[s2];
        }
    }

    float logy1 = (s1 < 192) ? __logf(acc + addLo) : lyHi;
    float x1 = 0.5f * (MSG[e * S + s1] + uD + v1 - bt1 + mPrev + logy1);
    float x2 = 1e30f;
    if (s2 < S) {
        x2 = 0.5f * (MSG[e * S + s2] + uD + v2 - bt2 + mPrev + lyHi);
        MSG[e * S + s2] = x2;
    }
    MSG[e * S + s1] = x1;

    red[t] = fminf(x1, x2);
    __syncthreads();
    for (int o = 128; o; o >>= 1) {
        if (t < o) red[t] = fminf(red[t], red[t + o]);
        __syncthreads();
    }
    float mn = red[0];
    __syncthreads();

    float mx1 = __expf(mn - x1);
    float mx2 = (s2 < S) ? __expf(mn - x2) : 0.f;
    MX[e * S + s1] = mx1;
    if (s2 < S) MX[e * S + s2] = mx2;
    if (t == 0) {
        if (fwd) ws[OFF_MAXF + e] = -mn; else ws[OFF_MAXB + e] = -mn;
    }

    red[t]  = (t < 192) ? mx1 : 0.f;
    red2[t] = ((t >= 192) ? mx1 : 0.f) + mx2;
    __syncthreads();
    for (int o = 128; o; o >>= 1) {
        if (t < o) { red[t] += red[t + o]; red2[t] += red2[t + o]; }
        __syncthreads();
    }
    if (t == 0) {
        if (fwd) { ws[OFF_LOF + e] = red[0]; ws[OFF_HIF + e] = red2[0]; }
        else     { ws[OFF_LOB + e] = red[0]; ws[OFF_HIB + e] = red2[0]; }
    }
}

// final: out[a][b] = exp(min(btFinal[a][b] - U[a] - V[b], 0))
//   btFinal = phie + gather(MSGF) + gather(MSGB); rows a>=192: bt=0, U=uhi
__global__ __launch_bounds__(256) void k_final(const float* __restrict__ ws,
                                               float* __restrict__ out)
{
    int t = threadIdx.x;
    const int* ip = (const int*)(ws + OFF_INT);
    const float* V = ws + OFF_V;
    float uhi = ws[OFF_UHI];

    for (int a = blockIdx.x * 6; a < blockIdx.x * 6 + 6; ++a) {
        if (a < 192) {
            float ua = ws[OFF_U + a];
            int cF = ip[IOFF_CNTF + a], cB = ip[IOFF_CNTB + a];
            const int* aF = ip + IOFF_ADJF + a * MAXADJ;
            const int* aB = ip + IOFF_ADJB + a * MAXADJ;
            for (int b = t; b < S; b += 256) {
                float bt = ws[OFF_PHIE + a * S + b];
                for (int q = 0; q < cF; ++q) bt += ws[OFF_MSGF + aF[q] * S + b];
                for (int q = 0; q < cB; ++q) bt += ws[OFF_MSGB + aB[q] * S + b];
                out[a * S + b] = __expf(fminf(bt - ua - V[b], 0.f));
            }
        } else {
            for (int b = t; b < S; b += 256)
                out[a * S + b] = __expf(fminf(-uhi - V[b], 0.f));
        }
    }
}

// ---------------------------------------------------------------------------
extern "C" void kernel_launch(void* const* d_in, const int* in_sizes, int n_in,
                              void* d_out, int out_size, void* d_ws, size_t ws_size,
                              hipStream_t stream)
{
    const int*   E1f    = (const int*)d_in[0];
    const int*   E1b    = (const int*)d_in[1];
    const float* cost   = (const float*)d_in[3];
    const float* constr = (const float*)d_in[4];

    float* ws = (float*)d_ws;

    k_setup<<<64, 256, 0, stream>>>(E1f, E1b, cost, constr, ws);

    for (int step = 0; step < 8; ++step) {
        k_uv1<<<49, 256, 0, stream>>>(ws);
        k_msg<<<NE, 256, 0, stream>>>(ws, 1);
        k_msg<<<NE, 256, 0, stream>>>(ws, 0);
    }

    k_final<<<64, 256, 0, stream>>>(ws, (float*)d_out);
}